// Round 6
// baseline (703.331 us; speedup 1.0000x reference)
//
#include <hip/hip_runtime.h>
#include <math.h>

#define Bsz 4
#define Tsz 5
#define Csz 64
#define Fsz 10
#define Hsz 48
#define Wsz 48
#define HWsz (Hsz*Wsz)          // 2304
#define Nsz (Tsz*HWsz)          // 11520
#define N4  (Nsz/4)             // 2880 float4 per W row

typedef float float4n __attribute__((ext_vector_type(4)));

// ws layout (floats):
#define O_S   0                          // st  [N][B]  (s transposed, float4 per n)
#define O_G3  (O_S + Bsz*Nsz)            // g3t [B][F][N]
#define O_Z   (O_G3 + Bsz*Fsz*Nsz)       // z   [B][N]
#define O_MX  (O_Z + Bsz*Nsz)
#define O_SM  (O_MX + 4)

// ---- kernel 1: one pass over input -> st[n][b] and g3t[b][f][n] ----
// conv1+avgpool folded analytically: s = x . mean_f(conv1_w) + mean_f(conv1_b)
__global__ __launch_bounds__(256) void k_sg3(const float* __restrict__ in,
                                             const float* __restrict__ cw,
                                             const float* __restrict__ cb,
                                             const float* __restrict__ g3w,
                                             const float* __restrict__ g3b,
                                             float* __restrict__ ws) {
    __shared__ float sw[Fsz*Csz];   // g3 weights
    __shared__ float scw[Csz + 1];  // folded conv1 weights + bias
    if (threadIdx.x < Csz) {
        float a = 0.f;
        #pragma unroll
        for (int f = 0; f < Fsz; ++f) a += cw[f*Csz + threadIdx.x];
        scw[threadIdx.x] = a * (1.0f/Fsz);
    }
    if (threadIdx.x == 0) {
        float a = 0.f;
        #pragma unroll
        for (int f = 0; f < Fsz; ++f) a += cb[f];
        scw[Csz] = a * (1.0f/Fsz);
    }
    for (int i = threadIdx.x; i < Fsz*Csz; i += 256) sw[i] = g3w[i];
    __syncthreads();

    const int n = blockIdx.x * 256 + threadIdx.x;   // 2304 % 256 == 0 -> t uniform per block
    const int b = blockIdx.y;
    const int t = n / HWsz;
    const int p = n - t * HWsz;

    const float* xp = in + ((size_t)(b*Tsz + t) * Csz) * HWsz + p;  // stride HWsz per c

    float accs = 0.f;
    float accf[Fsz];
    #pragma unroll
    for (int f = 0; f < Fsz; ++f) accf[f] = 0.f;

    for (int c = 0; c < Csz; ++c) {
        float xv = xp[(size_t)c * HWsz];
        accs = fmaf(xv, scw[c], accs);
        #pragma unroll
        for (int f = 0; f < Fsz; ++f) accf[f] = fmaf(xv, sw[f*Csz + c], accf[f]);
    }

    float* st  = ws + O_S;
    float* g3t = ws + O_G3;
    st[n*4 + b] = accs + scw[Csz];          // transposed: [n][b]
    #pragma unroll
    for (int f = 0; f < Fsz; ++f)
        g3t[((size_t)b*Fsz + f) * Nsz + n] = accf[f] + g3b[f];
}

// ---- kernel 2: z = s @ W^T + fb ----
// Barrier-free: st[n][b] is L2-resident (184 KB); each lane reads 64 B of st
// per 64 B of W. W streamed nontemporal (read-once, don't evict st from L2).
__global__ __launch_bounds__(256) void k_gemv(const float* __restrict__ Wm,
                                              const float* __restrict__ fb,
                                              float* __restrict__ ws) {
    const int wave = threadIdx.x >> 6;
    const int lane = threadIdx.x & 63;
    const int row0 = blockIdx.x * 16 + wave * 4;

    const float4n* w0 = (const float4n*)(Wm + (size_t)(row0    ) * Nsz);
    const float4n* w1 = (const float4n*)(Wm + (size_t)(row0 + 1) * Nsz);
    const float4n* w2 = (const float4n*)(Wm + (size_t)(row0 + 2) * Nsz);
    const float4n* w3 = (const float4n*)(Wm + (size_t)(row0 + 3) * Nsz);
    const float4n* st = (const float4n*)(ws + O_S);   // st[n] = {s[0][n],s[1][n],s[2][n],s[3][n]}

    float acc[4][4];   // [row][batch]
    #pragma unroll
    for (int r = 0; r < 4; ++r)
        #pragma unroll
        for (int b = 0; b < 4; ++b) acc[r][b] = 0.f;

    for (int it = 0; it < N4/64; ++it) {     // 45 iters, no barriers
        const int j = it*64 + lane;          // float4 index into the W rows
        const float4n a0 = __builtin_nontemporal_load(w0 + j);
        const float4n a1 = __builtin_nontemporal_load(w1 + j);
        const float4n a2 = __builtin_nontemporal_load(w2 + j);
        const float4n a3 = __builtin_nontemporal_load(w3 + j);
        const float4n s0 = st[4*j + 0];
        const float4n s1 = st[4*j + 1];
        const float4n s2 = st[4*j + 2];
        const float4n s3 = st[4*j + 3];
        #pragma unroll
        for (int b = 0; b < 4; ++b) {
            acc[0][b] = fmaf(a0.x, s0[b], acc[0][b]); acc[0][b] = fmaf(a0.y, s1[b], acc[0][b]);
            acc[0][b] = fmaf(a0.z, s2[b], acc[0][b]); acc[0][b] = fmaf(a0.w, s3[b], acc[0][b]);
            acc[1][b] = fmaf(a1.x, s0[b], acc[1][b]); acc[1][b] = fmaf(a1.y, s1[b], acc[1][b]);
            acc[1][b] = fmaf(a1.z, s2[b], acc[1][b]); acc[1][b] = fmaf(a1.w, s3[b], acc[1][b]);
            acc[2][b] = fmaf(a2.x, s0[b], acc[2][b]); acc[2][b] = fmaf(a2.y, s1[b], acc[2][b]);
            acc[2][b] = fmaf(a2.z, s2[b], acc[2][b]); acc[2][b] = fmaf(a2.w, s3[b], acc[2][b]);
            acc[3][b] = fmaf(a3.x, s0[b], acc[3][b]); acc[3][b] = fmaf(a3.y, s1[b], acc[3][b]);
            acc[3][b] = fmaf(a3.z, s2[b], acc[3][b]); acc[3][b] = fmaf(a3.w, s3[b], acc[3][b]);
        }
    }

    #pragma unroll
    for (int r = 0; r < 4; ++r)
        #pragma unroll
        for (int b = 0; b < 4; ++b)
            #pragma unroll
            for (int off = 32; off > 0; off >>= 1)
                acc[r][b] += __shfl_xor(acc[r][b], off, 64);

    if (lane == 0) {
        float* z = ws + O_Z;
        #pragma unroll
        for (int r = 0; r < 4; ++r) {
            const float bias = fb[row0 + r];
            #pragma unroll
            for (int b = 0; b < 4; ++b)
                z[(size_t)b*Nsz + row0 + r] = acc[r][b] + bias;
        }
    }
}

// ---- kernel 3a: per-batch softmax stats (max, sum exp) ----
__global__ __launch_bounds__(256) void k_stats(float* __restrict__ ws) {
    const int b = blockIdx.x;
    const float* zb = (const float*)ws + O_Z + (size_t)b * Nsz;
    const int lane = threadIdx.x & 63;
    const int wave = threadIdx.x >> 6;
    __shared__ float red[4];
    __shared__ float bcast;

    float m = -INFINITY;
    for (int i = threadIdx.x; i < Nsz; i += 256) m = fmaxf(m, zb[i]);
    #pragma unroll
    for (int off = 32; off > 0; off >>= 1) m = fmaxf(m, __shfl_xor(m, off, 64));
    if (lane == 0) red[wave] = m;
    __syncthreads();
    if (threadIdx.x == 0)
        bcast = fmaxf(fmaxf(red[0], red[1]), fmaxf(red[2], red[3]));
    __syncthreads();
    m = bcast;

    float sum = 0.f;
    for (int i = threadIdx.x; i < Nsz; i += 256) sum += expf(zb[i] - m);
    #pragma unroll
    for (int off = 32; off > 0; off >>= 1) sum += __shfl_xor(sum, off, 64);
    if (lane == 0) red[wave] = sum;
    __syncthreads();
    if (threadIdx.x == 0) {
        ws[O_MX + b] = m;
        ws[O_SM + b] = red[0] + red[1] + red[2] + red[3];
    }
}

// ---- kernel 3b: gate + scale g3, write [B,T,F,H,W] ----
__global__ __launch_bounds__(256) void k_out(const float* __restrict__ aw,
                                             const float* __restrict__ ws,
                                             float* __restrict__ out) {
    const int n = blockIdx.x * 256 + threadIdx.x;
    const int b = blockIdx.y;

    const float zv  = ws[O_Z + (size_t)b*Nsz + n];
    const float a0 = aw[0], a1 = aw[1], a2 = aw[2];
    const float mxb = ws[O_MX + b];
    const float smb = ws[O_SM + b];

    const float gate = a0 * fmaxf(zv, 0.f)
                     + a1 / (1.f + expf(-zv))
                     + a2 * expf(zv - mxb) / smb;

    const int t = n / HWsz;
    const int p = n - t * HWsz;
    const float* gp = ws + O_G3 + (size_t)b * Fsz * Nsz + n;       // [b][f][n]
    float* ob = out + ((size_t)(b*Tsz + t) * Fsz) * HWsz + p;      // [b][t][f][p]
    #pragma unroll
    for (int f = 0; f < Fsz; ++f)
        ob[(size_t)f * HWsz] = gate * gp[(size_t)f * Nsz];
}

extern "C" void kernel_launch(void* const* d_in, const int* in_sizes, int n_in,
                              void* d_out, int out_size, void* d_ws, size_t ws_size,
                              hipStream_t stream) {
    const float* input  = (const float*)d_in[0];
    // d_in[1] = input1 — unused by the reference
    const float* aw     = (const float*)d_in[2];
    const float* conv1w = (const float*)d_in[3];
    const float* conv1b = (const float*)d_in[4];
    const float* g3w    = (const float*)d_in[5];
    const float* g3b    = (const float*)d_in[6];
    const float* ffnw   = (const float*)d_in[7];
    const float* ffnb   = (const float*)d_in[8];
    float* out = (float*)d_out;
    float* ws  = (float*)d_ws;

    k_sg3  <<<dim3(Nsz/256, Bsz), 256, 0, stream>>>(input, conv1w, conv1b, g3w, g3b, ws);
    k_gemv <<<Nsz/16, 256, 0, stream>>>(ffnw, ffnb, ws);
    k_stats<<<Bsz, 256, 0, stream>>>(ws);
    k_out  <<<dim3(Nsz/256, Bsz), 256, 0, stream>>>(aw, ws, out);
}